// Round 14
// baseline (6438.356 us; speedup 1.0000x reference)
//
#include <hip/hip_runtime.h>

#define T_STEPS 512
#define BB 64
#define EE 300
#define EP 320
#define HH 512
#define HB (BB*HH)   // halves per h slot
#define RING 8
#define NCOL 16      // output columns per WG (all 16 MFMA cols real)
#define NWG 32       // WGs per layer

typedef _Float16 f16x8 __attribute__((ext_vector_type(8)));
typedef float f32x4 __attribute__((ext_vector_type(4)));
typedef int i32x4 __attribute__((ext_vector_type(4)));

__device__ __forceinline__ f32x4 mf(f16x8 a, f16x8 b, f32x4 c) {
  return __builtin_amdgcn_mfma_f32_16x16x32_f16(a, b, c, 0, 0, 0);
}

struct HMat { i32x4 q[16]; };   // 64 VGPRs: one lane's 16 A-fragments of a 64x512 f16 matrix

// 16 back-to-back MALL (sc1) 16B loads + FULL drain in ONE asm block
// (in-flight regs never escape a block — round-4 lesson). Proven h-data path.
#define LOADS16_MALL                                                 \
    "global_load_dwordx4 %0,  %16, %17 sc1\n\t"                      \
    "global_load_dwordx4 %1,  %16, %17 offset:64 sc1\n\t"            \
    "global_load_dwordx4 %2,  %16, %17 offset:128 sc1\n\t"           \
    "global_load_dwordx4 %3,  %16, %17 offset:192 sc1\n\t"           \
    "global_load_dwordx4 %4,  %16, %17 offset:256 sc1\n\t"           \
    "global_load_dwordx4 %5,  %16, %17 offset:320 sc1\n\t"           \
    "global_load_dwordx4 %6,  %16, %17 offset:384 sc1\n\t"           \
    "global_load_dwordx4 %7,  %16, %17 offset:448 sc1\n\t"           \
    "global_load_dwordx4 %8,  %16, %17 offset:512 sc1\n\t"           \
    "global_load_dwordx4 %9,  %16, %17 offset:576 sc1\n\t"           \
    "global_load_dwordx4 %10, %16, %17 offset:640 sc1\n\t"           \
    "global_load_dwordx4 %11, %16, %17 offset:704 sc1\n\t"           \
    "global_load_dwordx4 %12, %16, %17 offset:768 sc1\n\t"           \
    "global_load_dwordx4 %13, %16, %17 offset:832 sc1\n\t"           \
    "global_load_dwordx4 %14, %16, %17 offset:896 sc1\n\t"           \
    "global_load_dwordx4 %15, %16, %17 offset:960 sc1\n\t"           \
    "s_waitcnt vmcnt(0)"

#define HM_OUTS(m) "=v"((m).q[0]), "=v"((m).q[1]), "=v"((m).q[2]), "=v"((m).q[3]),   \
                   "=v"((m).q[4]), "=v"((m).q[5]), "=v"((m).q[6]), "=v"((m).q[7]),   \
                   "=v"((m).q[8]), "=v"((m).q[9]), "=v"((m).q[10]), "=v"((m).q[11]), \
                   "=v"((m).q[12]), "=v"((m).q[13]), "=v"((m).q[14]), "=v"((m).q[15])

__device__ __forceinline__ void load16_mall(HMat& m, const void* base, int voff) {
  asm volatile(LOADS16_MALL : HM_OUTS(m) : "v"(voff), "s"(base) : "memory");
}

// batched x-prefetch: 10 plain cached loads + full drain (x0 is immutable)
__device__ __forceinline__ void loadx10_wait(i32x4* xq, const void* base, int voff) {
  asm volatile(
    "global_load_dwordx4 %0, %10, %11\n\t"
    "global_load_dwordx4 %1, %10, %11 offset:64\n\t"
    "global_load_dwordx4 %2, %10, %11 offset:128\n\t"
    "global_load_dwordx4 %3, %10, %11 offset:192\n\t"
    "global_load_dwordx4 %4, %10, %11 offset:256\n\t"
    "global_load_dwordx4 %5, %10, %11 offset:320\n\t"
    "global_load_dwordx4 %6, %10, %11 offset:384\n\t"
    "global_load_dwordx4 %7, %10, %11 offset:448\n\t"
    "global_load_dwordx4 %8, %10, %11 offset:512\n\t"
    "global_load_dwordx4 %9, %10, %11 offset:576\n\t"
    "s_waitcnt vmcnt(0)"
    : "=v"(xq[0]), "=v"(xq[1]), "=v"(xq[2]), "=v"(xq[3]), "=v"(xq[4]),
      "=v"(xq[5]), "=v"(xq[6]), "=v"(xq[7]), "=v"(xq[8]), "=v"(xq[9])
    : "v"(voff), "s"(base) : "memory");
}

__device__ __forceinline__ f16x8 fragq(i32x4 q) {
  union { i32x4 i; f16x8 v; } x; x.i = q; return x.v;
}

// h-tile publish to MALL (proven pair with sc1 loads)
__device__ __forceinline__ void st16_mall(void* p, f16x8 v) {
  i32x4 iv;
  __builtin_memcpy(&iv, &v, 16);
  asm volatile("global_store_dwordx4 %0, %1, off sc0 sc1" :: "v"(p), "v"(iv) : "memory");
}

// device-scope flag word publish / poll
__device__ __forceinline__ void st4_dev(int* p, int v) {
  asm volatile("global_store_dword %0, %1, off sc0 sc1" :: "v"(p), "v"(v) : "memory");
}
__device__ __forceinline__ int ld4_dev(const int* p) {
  int r;
  asm volatile("global_load_dword %0, %1, off sc1\n\ts_waitcnt vmcnt(0)"
               : "=v"(r) : "v"(p) : "memory");
  return r;
}

// WG wait on monotone value flags (one word per producer WG, 64B apart,
// NWG=32 producers; lanes duplicate via &31). Wave 0 polls edge A, wave 1
// edge B concurrently; one barrier releases. Sleep backoff caps poll pressure.
__device__ __forceinline__ void wg_waitv(const int* fA, int tA, const int* fB, int tB) {
  const int wv = threadIdx.x >> 6, lane = threadIdx.x & 63;
  if (wv == 0 && fA) {
    const int* q = fA + (lane & 31) * 16;
    while (!__all(ld4_dev(q) >= tA)) __builtin_amdgcn_s_sleep(2);
  } else if (wv == 1 && fB) {
    const int* q = fB + (lane & 31) * 16;
    while (!__all(ld4_dev(q) >= tB)) __builtin_amdgcn_s_sleep(2);
  }
  __syncthreads();
}

__device__ __forceinline__ float sigf(float x) { return 1.f / (1.f + __expf(-x)); }

struct B3 { f16x8 r, z, n; };
// LDS weight read: [chunk][gate(3)][jj(16)][40 halves] — jj-stride 40 (80 B)
// spreads bank bases over all 32 banks: 8-way conflict -> 2-way (free, m136).
__device__ __forceinline__ B3 ldsB(const _Float16* wl, int chunk, int jj, int kq) {
  B3 o;
  const _Float16* p = wl + chunk * 1920 + jj * 40 + kq;
  o.r = *(const f16x8*)p;
  o.z = *(const f16x8*)(p + 640);
  o.n = *(const f16x8*)(p + 1280);
  return o;
}

__global__ void prep_x0(const int* __restrict__ texts, const float* __restrict__ emb,
                        _Float16* __restrict__ x0) {
  const size_t N = (size_t)T_STEPS * BB * EP;
  const size_t stride = (size_t)gridDim.x * blockDim.x;
  for (size_t i = (size_t)blockIdx.x * blockDim.x + threadIdx.x; i < N; i += stride) {
    int e = (int)(i % EP);
    size_t tb = i / EP;
    float v = 0.f;
    if (e < EE) v = emb[(size_t)texts[tb] * EE + e];
    x0[i] = (_Float16)v;
  }
}

__global__ void prep_b(const float* __restrict__ bih0, const float* __restrict__ bhh0,
                       const float* __restrict__ bih1, const float* __restrict__ bhh1,
                       float* __restrict__ bias0, float* __restrict__ bias1) {
  int i = blockIdx.x * blockDim.x + threadIdx.x;
  if (i < HH) {
    bias0[i]        = bih0[i] + bhh0[i];
    bias0[512 + i]  = bih0[512 + i] + bhh0[512 + i];
    bias0[1024 + i] = bih0[1024 + i];
    bias0[1536 + i] = bhh0[1024 + i];
    bias1[i]        = bih1[i] + bhh1[i];
    bias1[512 + i]  = bih1[512 + i] + bhh1[512 + i];
    bias1[1024 + i] = bih1[1024 + i];
    bias1[1536 + i] = bhh1[1024 + i];
  }
}

// 64 WGs x 256 threads. WG 0..31 = layer0 (16-col slices), 32..63 = layer1.
// Round-14: halve the per-stage h broadcast (12->6 MB: the r12/r13 plateau
// matched ~1 TB/s of MALL reads) by making all 16 MFMA cols real (NCOL=16,
// NWG=32) + bank-conflict-free padded weight layout. Chain structure = r13.
__global__ __launch_bounds__(256, 1) void gru_persistent(
    const _Float16* __restrict__ x0,
    const float* __restrict__ Wih0, const float* __restrict__ Whh0,
    const float* __restrict__ Wih1, const float* __restrict__ Whh1,
    const float* __restrict__ bias0, const float* __restrict__ bias1,
    _Float16* h1ring, _Float16* h2buf, float* pooled,
    int* flags0, int* flags1)
{
  const int wg   = blockIdx.x;
  const int L    = wg >> 5;
  const int w    = wg & 31;
  const int jb   = w * NCOL;
  const int tid  = threadIdx.x;
  const int bsub = tid >> 6;          // wave index: owns batch rows 16*bsub..+15
  const int lane = tid & 63;
  const int quad = lane >> 4;
  const int l15  = lane & 15;         // output column within slice (all real)
  const int brow = bsub * 16 + l15;   // A-operand row (batch)
  const int j    = jb + l15;          // output column (for bias)
  const int kq   = quad * 8;
  const int hoff = brow * (HH * 2) + quad * 16;   // byte voffset into an h slot

  __shared__ _Float16 wlds[61440];          // 122880 B: 32 chunks x 1920 halves
  __shared__ _Float16 tile[2][4][16][NCOL]; // 4096 B, wave-private b x j tiles

  // ---- one-time LDS weight fill from fp32 globals ----
  if (L == 0) {
    // chunks 0..9 = W0x (K=320, cols >=300 zero), 10..25 = W0h (K=512)
    for (int idx = tid; idx < 26 * 192; idx += 256) {
      int q = idx & 3, jj = (idx >> 2) & 15, g = (idx >> 6) % 3, ch = idx / 192;
      int row = g * 512 + jb + jj;
      _Float16* dst = wlds + ch * 1920 + g * 640 + jj * 40 + q * 8;
      if (ch < 10) {
        int colb = ch * 32 + q * 8;
        #pragma unroll
        for (int e = 0; e < 8; ++e) {
          int col = colb + e;
          dst[e] = (col < EE) ? (_Float16)Wih0[(size_t)row * EE + col] : (_Float16)0.f;
        }
      } else {
        int colb = (ch - 10) * 32 + q * 8;
        #pragma unroll
        for (int e = 0; e < 8; ++e)
          dst[e] = (_Float16)Whh0[(size_t)row * HH + colb + e];
      }
    }
  } else {
    // chunks 0..15 = W1x, 16..31 = W1h (both K=512)
    for (int idx = tid; idx < 32 * 192; idx += 256) {
      int q = idx & 3, jj = (idx >> 2) & 15, g = (idx >> 6) % 3, ch = idx / 192;
      int row = g * 512 + jb + jj;
      const float* src = (ch < 16) ? Wih1 : Whh1;
      int colb = ((ch < 16) ? ch : ch - 16) * 32 + q * 8;
      _Float16* dst = wlds + ch * 1920 + g * 640 + jj * 40 + q * 8;
      #pragma unroll
      for (int e = 0; e < 8; ++e)
        dst[e] = (_Float16)src[(size_t)row * HH + colb + e];
    }
  }
  __syncthreads();

  if (L == 0) {
    const float br = bias0[j], bz = bias0[512 + j];
    const float bnx = bias0[1024 + j], bnh = bias0[1536 + j];
    const int xoff = brow * (EP * 2) + quad * 16;
    // preloop: x-part for s=0 (off critical path)
    f32x4 xR = {0.f,0.f,0.f,0.f}, xZ = {0.f,0.f,0.f,0.f}, xN = {0.f,0.f,0.f,0.f};
    {
      i32x4 xq[10];
      loadx10_wait(xq, x0, xoff);
      #pragma unroll 5
      for (int c = 0; c < 10; ++c) {
        f16x8 a = fragq(xq[c]);
        B3 bb = ldsB(wlds, c, l15, kq);
        xR = mf(a, bb.r, xR); xZ = mf(a, bb.z, xZ); xN = mf(a, bb.n, xN);
      }
    }
    for (int s = 0; s < T_STEPS; ++s) {
      // ONE detect barrier: wave0 = own-layer all-to-all, wave1 = ring throttle
      wg_waitv((s >= 1)    ? flags0 : nullptr, s,
               (s >= RING) ? flags1 : nullptr, s - RING + 1);
      f32x4 hR = {0.f,0.f,0.f,0.f}, hZ = {0.f,0.f,0.f,0.f}, hN = {0.f,0.f,0.f,0.f};
      if (s >= 1) {
        HMat hA;
        load16_mall(hA, h1ring + ((s - 1) & (RING - 1)) * HB, hoff);
        #pragma unroll 4
        for (int c = 0; c < 16; ++c) {
          f16x8 a = fragq(hA.q[c]);
          B3 bb = ldsB(wlds, 10 + c, l15, kq);
          hR = mf(a, bb.r, hR); hZ = mf(a, bb.z, hZ); hN = mf(a, bb.n, hN);
        }
      }

      _Float16 (*tc)[NCOL] = tile[s & 1][bsub];
      _Float16 (*tp)[NCOL] = tile[(s + 1) & 1][bsub];
      #pragma unroll
      for (int rg = 0; rg < 4; ++rg) {
        const int rr = quad * 4 + rg;           // C/D row = quad*4+reg
        float r = sigf(xR[rg] + hR[rg] + br);
        float z = sigf(xZ[rg] + hZ[rg] + bz);
        float n = tanhf(xN[rg] + bnx + r * (hN[rg] + bnh));
        float hp = (s >= 1) ? (float)tp[rr][l15] : 0.f;
        tc[rr][l15] = (_Float16)((1.f - z) * n + z * hp);
      }
      if (lane < 32) {                          // publish own 16 rows x 32B
        const int row = lane >> 1, seg = lane & 1;
        f16x8 v = *(const f16x8*)&tc[row][seg * 8];
        st16_mall(h1ring + (s & (RING - 1)) * HB + (size_t)(bsub * 16 + row) * HH + jb + seg * 8, v);
      }
      __builtin_amdgcn_s_waitcnt(0);            // own h stores at MALL
      __syncthreads();                          // all 4 waves drained
      if (tid == 0) st4_dev(flags0 + w * 16, s + 1);   // one word, own line
      // TAIL (off critical path): x-prefetch + x-MFMA for s+1
      if (s + 1 < T_STEPS) {
        i32x4 xq[10];
        loadx10_wait(xq, x0 + (size_t)(s + 1) * BB * EP, xoff);
        xR = (f32x4){0.f,0.f,0.f,0.f}; xZ = (f32x4){0.f,0.f,0.f,0.f};
        xN = (f32x4){0.f,0.f,0.f,0.f};
        #pragma unroll 5
        for (int c = 0; c < 10; ++c) {
          f16x8 a = fragq(xq[c]);
          B3 bb = ldsB(wlds, c, l15, kq);
          xR = mf(a, bb.r, xR); xZ = mf(a, bb.z, xZ); xN = mf(a, bb.n, xN);
        }
      }
    }
  } else {
    const float br = bias1[j], bz = bias1[512 + j];
    const float bnx = bias1[1024 + j], bnh = bias1[1536 + j];
    // preloop: prefetch h1[0] and its x-part accumulators (off critical path)
    f32x4 xR = {0.f,0.f,0.f,0.f}, xZ = {0.f,0.f,0.f,0.f}, xN = {0.f,0.f,0.f,0.f};
    {
      wg_waitv(flags0, 1, nullptr, 0);
      HMat A1;
      load16_mall(A1, h1ring, hoff);
      #pragma unroll 4
      for (int c = 0; c < 16; ++c) {
        f16x8 a = fragq(A1.q[c]);
        B3 bb = ldsB(wlds, c, l15, kq);
        xR = mf(a, bb.r, xR); xZ = mf(a, bb.z, xZ); xN = mf(a, bb.n, xN);
      }
    }
    for (int t = 0; t < T_STEPS; ++t) {
      // ONE fused detect: wave0 = self-recurrence (critical), wave1 = L0 lead
      wg_waitv((t >= 1) ? flags1 : nullptr, t,
               (t + 1 < T_STEPS) ? flags0 : nullptr, t + 2);
      f32x4 hR = {0.f,0.f,0.f,0.f}, hZ = {0.f,0.f,0.f,0.f}, hN = {0.f,0.f,0.f,0.f};
      if (t >= 1) {
        HMat A2;
        load16_mall(A2, h2buf + ((t - 1) & 1) * HB, hoff);
        #pragma unroll 4
        for (int c = 0; c < 16; ++c) {
          f16x8 a = fragq(A2.q[c]);
          B3 bb = ldsB(wlds, 16 + c, l15, kq);
          hR = mf(a, bb.r, hR); hZ = mf(a, bb.z, hZ); hN = mf(a, bb.n, hN);
        }
      }

      _Float16 (*tc)[NCOL] = tile[t & 1][bsub];
      _Float16 (*tp)[NCOL] = tile[(t + 1) & 1][bsub];
      #pragma unroll
      for (int rg = 0; rg < 4; ++rg) {
        const int rr = quad * 4 + rg;
        float r = sigf(xR[rg] + hR[rg] + br);
        float z = sigf(xZ[rg] + hZ[rg] + bz);
        float n = tanhf(xN[rg] + bnx + r * (hN[rg] + bnh));
        float hp = (t >= 1) ? (float)tp[rr][l15] : 0.f;
        tc[rr][l15] = (_Float16)((1.f - z) * n + z * hp);
      }
      if (lane < 32) {
        const int row = lane >> 1, seg = lane & 1;
        f16x8 v = *(const f16x8*)&tc[row][seg * 8];
        st16_mall(h2buf + (t & 1) * HB + (size_t)(bsub * 16 + row) * HH + jb + seg * 8, v);
      }
      __builtin_amdgcn_s_waitcnt(0);
      __syncthreads();
      if (tid == 0) st4_dev(flags1 + w * 16, t + 1);

      // TAIL (off critical path): pooled partial, A1[t+1] load + x-part MFMAs
      if (lane < 16) {
        float sum = 0.f;
        #pragma unroll
        for (int r = 0; r < 16; ++r) sum += (float)tc[r][lane];
        atomicAdd(pooled + (size_t)t * HH + jb + lane, sum);   // raw sum; /64 in FC
      }
      if (t + 1 < T_STEPS) {
        HMat A1;
        load16_mall(A1, h1ring + ((t + 1) & (RING - 1)) * HB, hoff);
        xR = (f32x4){0.f,0.f,0.f,0.f}; xZ = (f32x4){0.f,0.f,0.f,0.f};
        xN = (f32x4){0.f,0.f,0.f,0.f};
        #pragma unroll 4
        for (int c = 0; c < 16; ++c) {
          f16x8 a = fragq(A1.q[c]);
          B3 bb = ldsB(wlds, c, l15, kq);
          xR = mf(a, bb.r, xR); xZ = mf(a, bb.z, xZ); xN = mf(a, bb.n, xN);
        }
      }
    }
  }
}

__global__ void fc_kernel(const float* __restrict__ pooled, const float* __restrict__ fcW,
                          const float* __restrict__ fcb, float* __restrict__ out) {
  const int t = blockIdx.x;
  const int lane = threadIdx.x;  // 64 = one wave
  float a0 = 0.f, a1 = 0.f, a2 = 0.f, a3 = 0.f, a4 = 0.f;
  for (int jj = lane; jj < HH; jj += 64) {
    float p = pooled[(size_t)t * HH + jj];
    a0 += p * fcW[jj];
    a1 += p * fcW[512 + jj];
    a2 += p * fcW[1024 + jj];
    a3 += p * fcW[1536 + jj];
    a4 += p * fcW[2048 + jj];
  }
  #pragma unroll
  for (int off = 32; off > 0; off >>= 1) {
    a0 += __shfl_down(a0, off, 64);
    a1 += __shfl_down(a1, off, 64);
    a2 += __shfl_down(a2, off, 64);
    a3 += __shfl_down(a3, off, 64);
    a4 += __shfl_down(a4, off, 64);
  }
  if (lane == 0) {
    const float sc = 1.f / 64.f;
    out[t * 5 + 0] = a0 * sc + fcb[0];
    out[t * 5 + 1] = a1 * sc + fcb[1];
    out[t * 5 + 2] = a2 * sc + fcb[2];
    out[t * 5 + 3] = a3 * sc + fcb[3];
    out[t * 5 + 4] = a4 * sc + fcb[4];
  }
}

extern "C" void kernel_launch(void* const* d_in, const int* in_sizes, int n_in,
                              void* d_out, int out_size, void* d_ws, size_t ws_size,
                              hipStream_t stream) {
  const int*   texts = (const int*)  d_in[0];
  const float* emb   = (const float*)d_in[1];
  const float* Wih0  = (const float*)d_in[2];
  const float* Whh0  = (const float*)d_in[3];
  const float* bih0  = (const float*)d_in[4];
  const float* bhh0  = (const float*)d_in[5];
  const float* Wih1  = (const float*)d_in[6];
  const float* Whh1  = (const float*)d_in[7];
  const float* bih1  = (const float*)d_in[8];
  const float* bhh1  = (const float*)d_in[9];
  const float* fcW   = (const float*)d_in[10];
  const float* fcb   = (const float*)d_in[11];
  float* out = (float*)d_out;

  char* ws = (char*)d_ws;
  int*      flags0 = (int*)ws;                        // 4096 B: 32 words used, 64B apart
  int*      flags1 = (int*)(ws + 4096);               // 4096 B
  float*    pooled = (float*)(ws + 8192);             // 1048576 B [512][512] f32
  _Float16* h1ring = (_Float16*)(ws + 1056768);       // 524288 B (8 x 64x512 f16)
  _Float16* h2buf  = (_Float16*)(ws + 1581056);       // 131072 B (2 slots)
  _Float16* x0     = (_Float16*)(ws + 1712128);       // 20971520 B [512][64][320]
  float*    bias0  = (float*)(ws + 22683648);         // 8192 B (r,z,nx,nh)
  float*    bias1  = (float*)(ws + 22691840);         // 8192 B
  // total ws use: 22700032 B

  hipMemsetAsync(ws, 0, 1056768, stream);  // flags0 + flags1 + pooled = zeros
  prep_x0<<<4096, 256, 0, stream>>>(texts, emb, x0);
  prep_b<<<2, 256, 0, stream>>>(bih0, bhh0, bih1, bhh1, bias0, bias1);
  gru_persistent<<<64, 256, 0, stream>>>(x0, Wih0, Whh0, Wih1, Whh1, bias0, bias1,
                                         h1ring, h2buf, pooled, flags0, flags1);
  fc_kernel<<<512, 64, 0, stream>>>(pooled, fcW, fcb, out);
}

// Round 15
// 6422.673 us; speedup vs baseline: 1.0024x; 1.0024x over previous
//
#include <hip/hip_runtime.h>

#define T_STEPS 512
#define BB 64
#define EE 300
#define EP 320
#define HH 512
#define HB (BB*HH)   // halves per h slot
#define RING 8
#define NCOL 16      // output columns per WG (all 16 MFMA cols real)
#define NWG 32       // WGs per layer

typedef _Float16 f16x8 __attribute__((ext_vector_type(8)));
typedef float f32x4 __attribute__((ext_vector_type(4)));
typedef int i32x4 __attribute__((ext_vector_type(4)));

__device__ __forceinline__ f32x4 mf(f16x8 a, f16x8 b, f32x4 c) {
  return __builtin_amdgcn_mfma_f32_16x16x32_f16(a, b, c, 0, 0, 0);
}

struct HMat { i32x4 q[16]; };   // 64 VGPRs: one lane's 16 A-fragments of a 64x512 f16 matrix

// 16 back-to-back MALL (sc1) 16B loads + FULL drain in ONE asm block
// (in-flight regs never escape a block — round-4 lesson). Proven h-data path.
#define LOADS16_MALL                                                 \
    "global_load_dwordx4 %0,  %16, %17 sc1\n\t"                      \
    "global_load_dwordx4 %1,  %16, %17 offset:64 sc1\n\t"            \
    "global_load_dwordx4 %2,  %16, %17 offset:128 sc1\n\t"           \
    "global_load_dwordx4 %3,  %16, %17 offset:192 sc1\n\t"           \
    "global_load_dwordx4 %4,  %16, %17 offset:256 sc1\n\t"           \
    "global_load_dwordx4 %5,  %16, %17 offset:320 sc1\n\t"           \
    "global_load_dwordx4 %6,  %16, %17 offset:384 sc1\n\t"           \
    "global_load_dwordx4 %7,  %16, %17 offset:448 sc1\n\t"           \
    "global_load_dwordx4 %8,  %16, %17 offset:512 sc1\n\t"           \
    "global_load_dwordx4 %9,  %16, %17 offset:576 sc1\n\t"           \
    "global_load_dwordx4 %10, %16, %17 offset:640 sc1\n\t"           \
    "global_load_dwordx4 %11, %16, %17 offset:704 sc1\n\t"           \
    "global_load_dwordx4 %12, %16, %17 offset:768 sc1\n\t"           \
    "global_load_dwordx4 %13, %16, %17 offset:832 sc1\n\t"           \
    "global_load_dwordx4 %14, %16, %17 offset:896 sc1\n\t"           \
    "global_load_dwordx4 %15, %16, %17 offset:960 sc1\n\t"           \
    "s_waitcnt vmcnt(0)"

#define HM_OUTS(m) "=v"((m).q[0]), "=v"((m).q[1]), "=v"((m).q[2]), "=v"((m).q[3]),   \
                   "=v"((m).q[4]), "=v"((m).q[5]), "=v"((m).q[6]), "=v"((m).q[7]),   \
                   "=v"((m).q[8]), "=v"((m).q[9]), "=v"((m).q[10]), "=v"((m).q[11]), \
                   "=v"((m).q[12]), "=v"((m).q[13]), "=v"((m).q[14]), "=v"((m).q[15])

__device__ __forceinline__ void load16_mall(HMat& m, const void* base, int voff) {
  asm volatile(LOADS16_MALL : HM_OUTS(m) : "v"(voff), "s"(base) : "memory");
}

// batched x-prefetch: 10 plain cached loads + full drain (x0 is immutable)
__device__ __forceinline__ void loadx10_wait(i32x4* xq, const void* base, int voff) {
  asm volatile(
    "global_load_dwordx4 %0, %10, %11\n\t"
    "global_load_dwordx4 %1, %10, %11 offset:64\n\t"
    "global_load_dwordx4 %2, %10, %11 offset:128\n\t"
    "global_load_dwordx4 %3, %10, %11 offset:192\n\t"
    "global_load_dwordx4 %4, %10, %11 offset:256\n\t"
    "global_load_dwordx4 %5, %10, %11 offset:320\n\t"
    "global_load_dwordx4 %6, %10, %11 offset:384\n\t"
    "global_load_dwordx4 %7, %10, %11 offset:448\n\t"
    "global_load_dwordx4 %8, %10, %11 offset:512\n\t"
    "global_load_dwordx4 %9, %10, %11 offset:576\n\t"
    "s_waitcnt vmcnt(0)"
    : "=v"(xq[0]), "=v"(xq[1]), "=v"(xq[2]), "=v"(xq[3]), "=v"(xq[4]),
      "=v"(xq[5]), "=v"(xq[6]), "=v"(xq[7]), "=v"(xq[8]), "=v"(xq[9])
    : "v"(voff), "s"(base) : "memory");
}

__device__ __forceinline__ f16x8 fragq(i32x4 q) {
  union { i32x4 i; f16x8 v; } x; x.i = q; return x.v;
}

// h-tile publish to MALL (proven pair with sc1 loads)
__device__ __forceinline__ void st16_mall(void* p, f16x8 v) {
  i32x4 iv;
  __builtin_memcpy(&iv, &v, 16);
  asm volatile("global_store_dwordx4 %0, %1, off sc0 sc1" :: "v"(p), "v"(iv) : "memory");
}

// flag/epoch publish: device-scope atomic umax — executes at the MALL, making
// the line MALL-resident (plain stores don't write-allocate memory-side:
// r12-r14's 360 MB FETCH = polls missing to HBM). Monotone values, umax-safe.
__device__ __forceinline__ void at_umax_dev(int* p, int v) {
  asm volatile("global_atomic_umax %0, %1, off sc1" :: "v"(p), "v"(v) : "memory");
}
__device__ __forceinline__ int ld4_dev(const int* p) {
  int r;
  asm volatile("global_load_dword %0, %1, off sc1\n\ts_waitcnt vmcnt(0)"
               : "=v"(r) : "v"(p) : "memory");
  return r;
}

// Consumer wait: ONE lane per edge polls a single epoch copy (wave0 lane0 =
// edge A, wave1 lane0 = edge B); barrier releases all. ~130 polling lanes
// device-wide instead of ~8192 (the r12-r14 HBM poll storm).
__device__ __forceinline__ void wg_waitE(const int* eA, int tA,
                                         const int* eB, int tB, int copy) {
  const int wv = threadIdx.x >> 6, lane = threadIdx.x & 63;
  if (lane == 0) {
    if (wv == 0 && eA) {
      const int* q = eA + copy * 16;
      while (ld4_dev(q) < tA) __builtin_amdgcn_s_sleep(4);
    } else if (wv == 1 && eB) {
      const int* q = eB + copy * 16;
      while (ld4_dev(q) < tB) __builtin_amdgcn_s_sleep(4);
    }
  }
  __syncthreads();
}

__device__ __forceinline__ float sigf(float x) { return 1.f / (1.f + __expf(-x)); }

struct B3 { f16x8 r, z, n; };
// LDS weight read: [chunk][gate(3)][jj(16)][40 halves] — jj-stride 40 (80 B)
// spreads bank bases over all 32 banks (8-way conflict -> 2-way, free).
__device__ __forceinline__ B3 ldsB(const _Float16* wl, int chunk, int jj, int kq) {
  B3 o;
  const _Float16* p = wl + chunk * 1920 + jj * 40 + kq;
  o.r = *(const f16x8*)p;
  o.z = *(const f16x8*)(p + 640);
  o.n = *(const f16x8*)(p + 1280);
  return o;
}

__global__ void prep_x0(const int* __restrict__ texts, const float* __restrict__ emb,
                        _Float16* __restrict__ x0) {
  const size_t N = (size_t)T_STEPS * BB * EP;
  const size_t stride = (size_t)gridDim.x * blockDim.x;
  for (size_t i = (size_t)blockIdx.x * blockDim.x + threadIdx.x; i < N; i += stride) {
    int e = (int)(i % EP);
    size_t tb = i / EP;
    float v = 0.f;
    if (e < EE) v = emb[(size_t)texts[tb] * EE + e];
    x0[i] = (_Float16)v;
  }
}

__global__ void prep_b(const float* __restrict__ bih0, const float* __restrict__ bhh0,
                       const float* __restrict__ bih1, const float* __restrict__ bhh1,
                       float* __restrict__ bias0, float* __restrict__ bias1) {
  int i = blockIdx.x * blockDim.x + threadIdx.x;
  if (i < HH) {
    bias0[i]        = bih0[i] + bhh0[i];
    bias0[512 + i]  = bih0[512 + i] + bhh0[512 + i];
    bias0[1024 + i] = bih0[1024 + i];
    bias0[1536 + i] = bhh0[1024 + i];
    bias1[i]        = bih1[i] + bhh1[i];
    bias1[512 + i]  = bih1[512 + i] + bhh1[512 + i];
    bias1[1024 + i] = bih1[1024 + i];
    bias1[1536 + i] = bhh1[1024 + i];
  }
}

// 65 WGs x 256 threads. WG 0..31 = layer0 (16-col slices), 32..63 = layer1,
// WG 64 = aggregator (sole poller of producer flags; publishes layer epochs
// via device atomics into 8 replicated copies). Weights LDS-resident.
// Epochs live at flags0+512 / flags1+512 (same zeroed pages).
__global__ __launch_bounds__(256, 1) void gru_persistent(
    const _Float16* __restrict__ x0,
    const float* __restrict__ Wih0, const float* __restrict__ Whh0,
    const float* __restrict__ Wih1, const float* __restrict__ Whh1,
    const float* __restrict__ bias0, const float* __restrict__ bias1,
    _Float16* h1ring, _Float16* h2buf, float* pooled,
    int* flags0, int* flags1)
{
  const int tid = threadIdx.x;
  const int wg  = blockIdx.x;
  int* epoch0 = flags0 + 512;   // byte offset 2048 inside the flags0 page
  int* epoch1 = flags1 + 512;

  if (wg == 64) {   // ---- aggregator: one wave per layer ----
    const int wv = tid >> 6, lane = tid & 63;
    if (wv == 0) {
      for (int v = 1; v <= T_STEPS; ++v) {
        for (;;) {
          int ok = 1;
          if (lane < 32) ok = (ld4_dev(flags0 + lane * 16) >= v);
          if (__all(ok)) break;
        }
        if (lane < 8) at_umax_dev(epoch0 + lane * 16, v);
      }
    } else if (wv == 1) {
      for (int v = 1; v <= T_STEPS; ++v) {
        for (;;) {
          int ok = 1;
          if (lane < 32) ok = (ld4_dev(flags1 + lane * 16) >= v);
          if (__all(ok)) break;
        }
        if (lane < 8) at_umax_dev(epoch1 + lane * 16, v);
      }
    }
    return;
  }

  const int L    = wg >> 5;
  const int w    = wg & 31;
  const int jb   = w * NCOL;
  const int ec   = w & 7;             // epoch copy this WG polls
  const int bsub = tid >> 6;          // wave index: owns batch rows 16*bsub..+15
  const int lane = tid & 63;
  const int quad = lane >> 4;
  const int l15  = lane & 15;         // output column within slice (all real)
  const int brow = bsub * 16 + l15;   // A-operand row (batch)
  const int j    = jb + l15;          // output column (for bias)
  const int kq   = quad * 8;
  const int hoff = brow * (HH * 2) + quad * 16;   // byte voffset into an h slot

  __shared__ _Float16 wlds[61440];          // 122880 B: 32 chunks x 1920 halves
  __shared__ _Float16 tile[2][4][16][NCOL]; // 4096 B, wave-private b x j tiles

  // ---- one-time LDS weight fill from fp32 globals ----
  if (L == 0) {
    // chunks 0..9 = W0x (K=320, cols >=300 zero), 10..25 = W0h (K=512)
    for (int idx = tid; idx < 26 * 192; idx += 256) {
      int q = idx & 3, jj = (idx >> 2) & 15, g = (idx >> 6) % 3, ch = idx / 192;
      int row = g * 512 + jb + jj;
      _Float16* dst = wlds + ch * 1920 + g * 640 + jj * 40 + q * 8;
      if (ch < 10) {
        int colb = ch * 32 + q * 8;
        #pragma unroll
        for (int e = 0; e < 8; ++e) {
          int col = colb + e;
          dst[e] = (col < EE) ? (_Float16)Wih0[(size_t)row * EE + col] : (_Float16)0.f;
        }
      } else {
        int colb = (ch - 10) * 32 + q * 8;
        #pragma unroll
        for (int e = 0; e < 8; ++e)
          dst[e] = (_Float16)Whh0[(size_t)row * HH + colb + e];
      }
    }
  } else {
    // chunks 0..15 = W1x, 16..31 = W1h (both K=512)
    for (int idx = tid; idx < 32 * 192; idx += 256) {
      int q = idx & 3, jj = (idx >> 2) & 15, g = (idx >> 6) % 3, ch = idx / 192;
      int row = g * 512 + jb + jj;
      const float* src = (ch < 16) ? Wih1 : Whh1;
      int colb = ((ch < 16) ? ch : ch - 16) * 32 + q * 8;
      _Float16* dst = wlds + ch * 1920 + g * 640 + jj * 40 + q * 8;
      #pragma unroll
      for (int e = 0; e < 8; ++e)
        dst[e] = (_Float16)src[(size_t)row * HH + colb + e];
    }
  }
  __syncthreads();

  if (L == 0) {
    const float br = bias0[j], bz = bias0[512 + j];
    const float bnx = bias0[1024 + j], bnh = bias0[1536 + j];
    const int xoff = brow * (EP * 2) + quad * 16;
    // preloop: x-part for s=0 (off critical path)
    f32x4 xR = {0.f,0.f,0.f,0.f}, xZ = {0.f,0.f,0.f,0.f}, xN = {0.f,0.f,0.f,0.f};
    {
      i32x4 xq[10];
      loadx10_wait(xq, x0, xoff);
      #pragma unroll 5
      for (int c = 0; c < 10; ++c) {
        f16x8 a = fragq(xq[c]);
        B3 bb = ldsB(wlds, c, l15, kq);
        xR = mf(a, bb.r, xR); xZ = mf(a, bb.z, xZ); xN = mf(a, bb.n, xN);
      }
    }
    for (int s = 0; s < T_STEPS; ++s) {
      // ONE detect barrier: wave0 = own-layer epoch, wave1 = ring throttle
      wg_waitE((s >= 1)    ? epoch0 : nullptr, s,
               (s >= RING) ? epoch1 : nullptr, s - RING + 1, ec);
      f32x4 hR = {0.f,0.f,0.f,0.f}, hZ = {0.f,0.f,0.f,0.f}, hN = {0.f,0.f,0.f,0.f};
      if (s >= 1) {
        HMat hA;
        load16_mall(hA, h1ring + ((s - 1) & (RING - 1)) * HB, hoff);
        #pragma unroll 4
        for (int c = 0; c < 16; ++c) {
          f16x8 a = fragq(hA.q[c]);
          B3 bb = ldsB(wlds, 10 + c, l15, kq);
          hR = mf(a, bb.r, hR); hZ = mf(a, bb.z, hZ); hN = mf(a, bb.n, hN);
        }
      }

      _Float16 (*tc)[NCOL] = tile[s & 1][bsub];
      _Float16 (*tp)[NCOL] = tile[(s + 1) & 1][bsub];
      #pragma unroll
      for (int rg = 0; rg < 4; ++rg) {
        const int rr = quad * 4 + rg;           // C/D row = quad*4+reg
        float r = sigf(xR[rg] + hR[rg] + br);
        float z = sigf(xZ[rg] + hZ[rg] + bz);
        float n = tanhf(xN[rg] + bnx + r * (hN[rg] + bnh));
        float hp = (s >= 1) ? (float)tp[rr][l15] : 0.f;
        tc[rr][l15] = (_Float16)((1.f - z) * n + z * hp);
      }
      if (lane < 32) {                          // publish own 16 rows x 32B
        const int row = lane >> 1, seg = lane & 1;
        f16x8 v = *(const f16x8*)&tc[row][seg * 8];
        st16_mall(h1ring + (s & (RING - 1)) * HB + (size_t)(bsub * 16 + row) * HH + jb + seg * 8, v);
      }
      __builtin_amdgcn_s_waitcnt(0);            // own h stores at MALL
      __syncthreads();                          // all 4 waves drained
      if (tid == 0) at_umax_dev(flags0 + w * 16, s + 1);   // own line, atomic
      // TAIL (off critical path): x-prefetch + x-MFMA for s+1
      if (s + 1 < T_STEPS) {
        i32x4 xq[10];
        loadx10_wait(xq, x0 + (size_t)(s + 1) * BB * EP, xoff);
        xR = (f32x4){0.f,0.f,0.f,0.f}; xZ = (f32x4){0.f,0.f,0.f,0.f};
        xN = (f32x4){0.f,0.f,0.f,0.f};
        #pragma unroll 5
        for (int c = 0; c < 10; ++c) {
          f16x8 a = fragq(xq[c]);
          B3 bb = ldsB(wlds, c, l15, kq);
          xR = mf(a, bb.r, xR); xZ = mf(a, bb.z, xZ); xN = mf(a, bb.n, xN);
        }
      }
    }
  } else {
    const float br = bias1[j], bz = bias1[512 + j];
    const float bnx = bias1[1024 + j], bnh = bias1[1536 + j];
    // preloop: prefetch h1[0] and its x-part accumulators (off critical path)
    f32x4 xR = {0.f,0.f,0.f,0.f}, xZ = {0.f,0.f,0.f,0.f}, xN = {0.f,0.f,0.f,0.f};
    {
      wg_waitE(epoch0, 1, nullptr, 0, ec);
      HMat A1;
      load16_mall(A1, h1ring, hoff);
      #pragma unroll 4
      for (int c = 0; c < 16; ++c) {
        f16x8 a = fragq(A1.q[c]);
        B3 bb = ldsB(wlds, c, l15, kq);
        xR = mf(a, bb.r, xR); xZ = mf(a, bb.z, xZ); xN = mf(a, bb.n, xN);
      }
    }
    for (int t = 0; t < T_STEPS; ++t) {
      // ONE fused detect: wave0 = self-recurrence (critical), wave1 = L0 lead
      wg_waitE((t >= 1) ? epoch1 : nullptr, t,
               (t + 1 < T_STEPS) ? epoch0 : nullptr, t + 2, ec);
      f32x4 hR = {0.f,0.f,0.f,0.f}, hZ = {0.f,0.f,0.f,0.f}, hN = {0.f,0.f,0.f,0.f};
      if (t >= 1) {
        HMat A2;
        load16_mall(A2, h2buf + ((t - 1) & 1) * HB, hoff);
        #pragma unroll 4
        for (int c = 0; c < 16; ++c) {
          f16x8 a = fragq(A2.q[c]);
          B3 bb = ldsB(wlds, 16 + c, l15, kq);
          hR = mf(a, bb.r, hR); hZ = mf(a, bb.z, hZ); hN = mf(a, bb.n, hN);
        }
      }

      _Float16 (*tc)[NCOL] = tile[t & 1][bsub];
      _Float16 (*tp)[NCOL] = tile[(t + 1) & 1][bsub];
      #pragma unroll
      for (int rg = 0; rg < 4; ++rg) {
        const int rr = quad * 4 + rg;
        float r = sigf(xR[rg] + hR[rg] + br);
        float z = sigf(xZ[rg] + hZ[rg] + bz);
        float n = tanhf(xN[rg] + bnx + r * (hN[rg] + bnh));
        float hp = (t >= 1) ? (float)tp[rr][l15] : 0.f;
        tc[rr][l15] = (_Float16)((1.f - z) * n + z * hp);
      }
      if (lane < 32) {
        const int row = lane >> 1, seg = lane & 1;
        f16x8 v = *(const f16x8*)&tc[row][seg * 8];
        st16_mall(h2buf + (t & 1) * HB + (size_t)(bsub * 16 + row) * HH + jb + seg * 8, v);
      }
      __builtin_amdgcn_s_waitcnt(0);
      __syncthreads();
      if (tid == 0) at_umax_dev(flags1 + w * 16, t + 1);

      // TAIL (off critical path): pooled partial, A1[t+1] load + x-part MFMAs
      if (lane < 16) {
        float sum = 0.f;
        #pragma unroll
        for (int r = 0; r < 16; ++r) sum += (float)tc[r][lane];
        atomicAdd(pooled + (size_t)t * HH + jb + lane, sum);   // raw sum; /64 in FC
      }
      if (t + 1 < T_STEPS) {
        HMat A1;
        load16_mall(A1, h1ring + ((t + 1) & (RING - 1)) * HB, hoff);
        xR = (f32x4){0.f,0.f,0.f,0.f}; xZ = (f32x4){0.f,0.f,0.f,0.f};
        xN = (f32x4){0.f,0.f,0.f,0.f};
        #pragma unroll 4
        for (int c = 0; c < 16; ++c) {
          f16x8 a = fragq(A1.q[c]);
          B3 bb = ldsB(wlds, c, l15, kq);
          xR = mf(a, bb.r, xR); xZ = mf(a, bb.z, xZ); xN = mf(a, bb.n, xN);
        }
      }
    }
  }
}

__global__ void fc_kernel(const float* __restrict__ pooled, const float* __restrict__ fcW,
                          const float* __restrict__ fcb, float* __restrict__ out) {
  const int t = blockIdx.x;
  const int lane = threadIdx.x;  // 64 = one wave
  float a0 = 0.f, a1 = 0.f, a2 = 0.f, a3 = 0.f, a4 = 0.f;
  for (int jj = lane; jj < HH; jj += 64) {
    float p = pooled[(size_t)t * HH + jj];
    a0 += p * fcW[jj];
    a1 += p * fcW[512 + jj];
    a2 += p * fcW[1024 + jj];
    a3 += p * fcW[1536 + jj];
    a4 += p * fcW[2048 + jj];
  }
  #pragma unroll
  for (int off = 32; off > 0; off >>= 1) {
    a0 += __shfl_down(a0, off, 64);
    a1 += __shfl_down(a1, off, 64);
    a2 += __shfl_down(a2, off, 64);
    a3 += __shfl_down(a3, off, 64);
    a4 += __shfl_down(a4, off, 64);
  }
  if (lane == 0) {
    const float sc = 1.f / 64.f;
    out[t * 5 + 0] = a0 * sc + fcb[0];
    out[t * 5 + 1] = a1 * sc + fcb[1];
    out[t * 5 + 2] = a2 * sc + fcb[2];
    out[t * 5 + 3] = a3 * sc + fcb[3];
    out[t * 5 + 4] = a4 * sc + fcb[4];
  }
}

extern "C" void kernel_launch(void* const* d_in, const int* in_sizes, int n_in,
                              void* d_out, int out_size, void* d_ws, size_t ws_size,
                              hipStream_t stream) {
  const int*   texts = (const int*)  d_in[0];
  const float* emb   = (const float*)d_in[1];
  const float* Wih0  = (const float*)d_in[2];
  const float* Whh0  = (const float*)d_in[3];
  const float* bih0  = (const float*)d_in[4];
  const float* bhh0  = (const float*)d_in[5];
  const float* Wih1  = (const float*)d_in[6];
  const float* Whh1  = (const float*)d_in[7];
  const float* bih1  = (const float*)d_in[8];
  const float* bhh1  = (const float*)d_in[9];
  const float* fcW   = (const float*)d_in[10];
  const float* fcb   = (const float*)d_in[11];
  float* out = (float*)d_out;

  char* ws = (char*)d_ws;
  int*      flags0 = (int*)ws;                        // 4096 B: flags (32x64B) + epochs @+2048
  int*      flags1 = (int*)(ws + 4096);               // 4096 B
  float*    pooled = (float*)(ws + 8192);             // 1048576 B [512][512] f32
  _Float16* h1ring = (_Float16*)(ws + 1056768);       // 524288 B (8 x 64x512 f16)
  _Float16* h2buf  = (_Float16*)(ws + 1581056);       // 131072 B (2 slots)
  _Float16* x0     = (_Float16*)(ws + 1712128);       // 20971520 B [512][64][320]
  float*    bias0  = (float*)(ws + 22683648);         // 8192 B (r,z,nx,nh)
  float*    bias1  = (float*)(ws + 22691840);         // 8192 B
  // total ws use: 22700032 B

  hipMemsetAsync(ws, 0, 1056768, stream);  // flags+epochs + pooled = zeros
  prep_x0<<<4096, 256, 0, stream>>>(texts, emb, x0);
  prep_b<<<2, 256, 0, stream>>>(bih0, bhh0, bih1, bhh1, bias0, bias1);
  gru_persistent<<<65, 256, 0, stream>>>(x0, Wih0, Whh0, Wih1, Whh1, bias0, bias1,
                                         h1ring, h2buf, pooled, flags0, flags1);
  fc_kernel<<<512, 64, 0, stream>>>(pooled, fcW, fcb, out);
}